// Round 4
// baseline (141.436 us; speedup 1.0000x reference)
//
#include <hip/hip_runtime.h>

// B=32, N=512, D=256, M=64, HID=256, H2=128, T=16384, rows R=B*T=524288
typedef _Float16 f16;
typedef f16  f16x2 __attribute__((ext_vector_type(2)));
typedef f16  f16x8 __attribute__((ext_vector_type(8)));
typedef float f32x16 __attribute__((ext_vector_type(16)));
typedef unsigned int u32;

#define MFMA32 __builtin_amdgcn_mfma_f32_32x32x16_f16

static __device__ __forceinline__ f16x8 cvt8(float4 a, float4 b) {
    f16x8 v;
    v[0]=(f16)a.x; v[1]=(f16)a.y; v[2]=(f16)a.z; v[3]=(f16)a.w;
    v[4]=(f16)b.x; v[5]=(f16)b.y; v[6]=(f16)b.z; v[7]=(f16)b.w;
    return v;
}
static __device__ __forceinline__ u32 pack2(float a, float b) {
    f16x2 p; p[0]=(f16)a; p[1]=(f16)b;
    return __builtin_bit_cast(u32, p);
}
// packed f16 add / relu (VOP3P)
static __device__ __forceinline__ u32 pk_add(u32 a, u32 b) {
    u32 d; asm("v_pk_add_f16 %0, %1, %2" : "=v"(d) : "v"(a), "v"(b)); return d;
}
static __device__ __forceinline__ u32 pk_relu(u32 a) {
    u32 d; asm("v_pk_max_f16 %0, %1, 0" : "=v"(d) : "v"(a)); return d;
}

// ---------------------------------------------------------------------------
// Prepack: W1a (256x256), W1b (64x256), W2 (256x128) -> f16 MFMA A-operand
// fragment layout for 32x32x16: frag[mt][ks][lane][j] = W[k][col],
// k = 16*ks + 8*(lane>>5) + j, col = 32*mt + (lane&31).
// ---------------------------------------------------------------------------
__global__ __launch_bounds__(256) void prepack(
    const float* __restrict__ W1, const float* __restrict__ W2,
    f16* __restrict__ pa, f16* __restrict__ pb, f16* __restrict__ pc)
{
    const int idx = blockIdx.x * 256 + threadIdx.x;   // grid covers 114688
    int rel, fid, mt, ks;
    const int lane = (idx >> 3) & 63;
    const int j    = idx & 7;
    const int g8   = ((lane >> 5) << 3) + j;          // 8*(lane>>5)+j
    const int ln   = lane & 31;
    if (idx < 65536) {                 // W1a: [8 mt][16 ks]
        rel = idx; fid = rel >> 9; mt = fid >> 4; ks = fid & 15;
        int k = 16 * ks + g8, col = 32 * mt + ln;
        pa[rel] = (f16)W1[k * 256 + col];
    } else if (idx < 81920) {          // W1b: [8 mt][4 ks]
        rel = idx - 65536; fid = rel >> 9; mt = fid >> 2; ks = fid & 3;
        int k = 16 * ks + g8, col = 32 * mt + ln;
        pb[rel] = (f16)W1[(256 + k) * 256 + col];
    } else {                           // W2: [4 mt][16 ks]
        rel = idx - 81920; fid = rel >> 9; mt = fid >> 4; ks = fid & 15;
        int k = 16 * ks + g8, col = 32 * mt + ln;
        pc[rel] = (f16)W2[k * 128 + col];
    }
}

// ---------------------------------------------------------------------------
// Kernel 1: A[ir][c] = sum_k h[ir][k] * W1a[k][c] + b1[c], stored f16 in a
// gather-friendly permuted layout: uint2 index = ir*64 + g*32 + mt*4 + q.
// ---------------------------------------------------------------------------
__global__ __launch_bounds__(256) void ainit(
    const float* __restrict__ H,       // [16384, 256]
    const f16x8* __restrict__ pW1a,    // [8][16][64] frags
    const float* __restrict__ B1,      // [256]
    f16* __restrict__ Af)              // [16384, 256] permuted
{
    const int tid = threadIdx.x, wid = tid >> 6, lane = tid & 63;
    const int g = lane >> 5, ln = lane & 31;
    const long ir = (long)blockIdx.x * 32 + ln;

    const float4* h4 = (const float4*)(H + ir * 256);
    f16x8 hf[16];
    #pragma unroll
    for (int ks = 0; ks < 16; ++ks)
        hf[ks] = cvt8(h4[4 * ks + 2 * g], h4[4 * ks + 2 * g + 1]);

    const float4* b14 = (const float4*)B1;
    #pragma unroll
    for (int mi = 0; mi < 2; ++mi) {
        const int mt = wid * 2 + mi;
        f32x16 acc;
        #pragma unroll
        for (int q = 0; q < 4; ++q) {
            float4 bv = b14[8 * mt + 2 * q + g];
            acc[4*q+0] = bv.x; acc[4*q+1] = bv.y; acc[4*q+2] = bv.z; acc[4*q+3] = bv.w;
        }
        #pragma unroll
        for (int ks = 0; ks < 16; ++ks)
            acc = MFMA32(pW1a[(mt * 16 + ks) * 64 + lane], hf[ks], acc, 0, 0, 0);
        #pragma unroll
        for (int q = 0; q < 4; ++q) {
            uint2 w;
            w.x = pack2(acc[4*q+0], acc[4*q+1]);
            w.y = pack2(acc[4*q+2], acc[4*q+3]);
            ((uint2*)Af)[ir * 64 + g * 32 + mt * 4 + q] = w;
        }
    }
}

// ---------------------------------------------------------------------------
// Fused: h1 = relu(me@W1b + A[seg]); h2 = relu(h1@W2 + b2); out = h2@W3 + b3
// Register-lean: 256-thr blocks, NO LDS, all weights via L1/L2, JIT loads.
// Target <=170 total regs (80 AGPR acc + ~88 VGPR) -> 3 waves/SIMD.
// ---------------------------------------------------------------------------
__global__ __launch_bounds__(256, 3) void fused_mlp(
    const float* __restrict__ ME,      // [524288, 64]
    const int*   __restrict__ SEG,     // [16384]
    const f16*   __restrict__ Af,      // [16384, 256] permuted
    const f16x8* __restrict__ pW1b,    // [8][4][64] frags (32KB, L1-hot)
    const f16x8* __restrict__ pW2,     // [4][16][64] frags (64KB, L2-hot)
    const float* __restrict__ B2,      // [128]
    const float* __restrict__ W3,      // [128]
    const float* __restrict__ B3,      // [1]
    float* __restrict__ OUT)           // [524288]
{
    const int tid = threadIdx.x, wid = tid >> 6, lane = tid & 63;
    const int g = lane >> 5, ln = lane & 31;
    const long grow = (long)blockIdx.x * 128 + wid * 32 + ln;
    const int  arow = ((int)(grow >> 14) << 9) + SEG[(int)(grow & 16383)];

    // ME row fragments: k = 16s + 8g + j
    const float4* mb = (const float4*)(ME + grow * 64);
    f16x8 mef[4];
    #pragma unroll
    for (int s = 0; s < 4; ++s) mef[s] = cvt8(mb[4*s + 2*g], mb[4*s + 2*g + 1]);

    const uint4* AB = (const uint4*)Af;   // 16B units: row*32 + g*16 + mt*2 + u

    f32x16 acc2[4];
    #pragma unroll
    for (int m2 = 0; m2 < 4; ++m2)
        #pragma unroll
        for (int i = 0; i < 16; ++i) acc2[m2][i] = 0.f;

    #pragma unroll
    for (int mt = 0; mt < 8; ++mt) {
        // gathered A chunk for this mt (f16-packed, b1 baked in)
        const uint4 a0 = AB[(long)arow * 32 + g * 16 + mt * 2];
        const uint4 a1 = AB[(long)arow * 32 + g * 16 + mt * 2 + 1];

        // layer-1 partial: mw = me @ W1b (this mt's 32 cols), acc from 0
        f32x16 acc;
        #pragma unroll
        for (int i = 0; i < 16; ++i) acc[i] = 0.f;
        #pragma unroll
        for (int s = 0; s < 4; ++s)
            acc = MFMA32(pW1b[(mt * 4 + s) * 64 + lane], mef[s], acc, 0, 0, 0);

        // h1 = relu(A + mw) in packed f16 (pk_add + pk_max, no unpack)
        u32 hpt[8];
        hpt[0] = pk_relu(pk_add(pack2(acc[0],  acc[1]),  a0.x));
        hpt[1] = pk_relu(pk_add(pack2(acc[2],  acc[3]),  a0.y));
        hpt[2] = pk_relu(pk_add(pack2(acc[4],  acc[5]),  a0.z));
        hpt[3] = pk_relu(pk_add(pack2(acc[6],  acc[7]),  a0.w));
        hpt[4] = pk_relu(pk_add(pack2(acc[8],  acc[9]),  a1.x));
        hpt[5] = pk_relu(pk_add(pack2(acc[10], acc[11]), a1.y));
        hpt[6] = pk_relu(pk_add(pack2(acc[12], acc[13]), a1.z));
        hpt[7] = pk_relu(pk_add(pack2(acc[14], acc[15]), a1.w));

        // layer-2 feed: ks2 = 2*mt + tt
        #pragma unroll
        for (int tt = 0; tt < 2; ++tt) {
            u32 w0 = hpt[4*tt+0], w1 = hpt[4*tt+1];
            u32 w2 = hpt[4*tt+2], w3 = hpt[4*tt+3];
            asm("v_permlane32_swap_b32 %0, %1" : "+v"(w0), "+v"(w2));
            asm("v_permlane32_swap_b32 %0, %1" : "+v"(w1), "+v"(w3));
            int wv[4] = {(int)w0, (int)w1, (int)w2, (int)w3};
            f16x8 bf;
            __builtin_memcpy(&bf, wv, 16);
            const int ks2 = 2 * mt + tt;
            f16x8 w2f[4];
            #pragma unroll
            for (int m2 = 0; m2 < 4; ++m2)
                w2f[m2] = pW2[(m2 * 16 + ks2) * 64 + lane];
            #pragma unroll
            for (int m2 = 0; m2 < 4; ++m2)
                acc2[m2] = MFMA32(w2f[m2], bf, acc2[m2], 0, 0, 0);
        }
    }

    // phase 3: out = relu(h2 + b2) . W3 + b3
    const float4* b24 = (const float4*)B2;
    const float4* w34 = (const float4*)W3;
    float sum = 0.f;
    #pragma unroll
    for (int m2 = 0; m2 < 4; ++m2)
        #pragma unroll
        for (int q = 0; q < 4; ++q) {
            float4 bb = b24[8*m2 + 2*q + g];
            float4 ww = w34[8*m2 + 2*q + g];
            sum += fmaxf(acc2[m2][4*q+0] + bb.x, 0.f) * ww.x
                 + fmaxf(acc2[m2][4*q+1] + bb.y, 0.f) * ww.y
                 + fmaxf(acc2[m2][4*q+2] + bb.z, 0.f) * ww.z
                 + fmaxf(acc2[m2][4*q+3] + bb.w, 0.f) * ww.w;
        }
    sum += __shfl_xor(sum, 32, 64);     // combine the two g column-halves
    if (lane < 32) OUT[grow] = sum + B3[0];
}

// ---------------------------------------------------------------------------
extern "C" void kernel_launch(void* const* d_in, const int* in_sizes, int n_in,
                              void* d_out, int out_size, void* d_ws, size_t ws_size,
                              hipStream_t stream) {
    const float* h_inst = (const float*)d_in[0];
    const float* me     = (const float*)d_in[1];
    const int*   seg    = (const int*)d_in[2];
    const float* W1     = (const float*)d_in[3];
    const float* b1     = (const float*)d_in[4];
    const float* W2     = (const float*)d_in[5];
    const float* b2     = (const float*)d_in[6];
    const float* W3     = (const float*)d_in[7];
    const float* b3     = (const float*)d_in[8];
    float* out = (float*)d_out;

    char* ws = (char*)d_ws;
    f16* Af   = (f16*)ws;                                   // 8,388,608 B
    f16* pW1a = (f16*)(ws + 8388608);                       //   131,072 B
    f16* pW1b = (f16*)(ws + 8388608 + 131072);              //    32,768 B
    f16* pW2  = (f16*)(ws + 8388608 + 131072 + 32768);      //    65,536 B

    prepack<<<448, 256, 0, stream>>>(W1, W2, pW1a, pW1b, pW2);
    ainit<<<512, 256, 0, stream>>>(h_inst, (const f16x8*)pW1a, b1, Af);
    fused_mlp<<<4096, 256, 0, stream>>>(me, seg, Af, (const f16x8*)pW1b,
                                        (const f16x8*)pW2, b2, W3, b3, out);
}

// Round 5
// 84.173 us; speedup vs baseline: 1.6803x; 1.6803x over previous
//
#include <hip/hip_runtime.h>

// B=32, N=512, D=256, M=64, HID=256, H2=128, T=16384, rows R=B*T=524288
typedef _Float16 f16;
typedef f16  f16x2 __attribute__((ext_vector_type(2)));
typedef f16  f16x8 __attribute__((ext_vector_type(8)));
typedef float f32x16 __attribute__((ext_vector_type(16)));
typedef unsigned int u32;

#define MFMA32 __builtin_amdgcn_mfma_f32_32x32x16_f16
#define NT 4   // row-tiles (32 rows) per wave

static __device__ __forceinline__ f16x8 cvt8(float4 a, float4 b) {
    f16x8 v;
    v[0]=(f16)a.x; v[1]=(f16)a.y; v[2]=(f16)a.z; v[3]=(f16)a.w;
    v[4]=(f16)b.x; v[5]=(f16)b.y; v[6]=(f16)b.z; v[7]=(f16)b.w;
    return v;
}
static __device__ __forceinline__ u32 pack2(float a, float b) {
    f16x2 p; p[0]=(f16)a; p[1]=(f16)b;
    return __builtin_bit_cast(u32, p);
}
// packed f16 add / relu (VOP3P)
static __device__ __forceinline__ u32 pk_add(u32 a, u32 b) {
    u32 d; asm("v_pk_add_f16 %0, %1, %2" : "=v"(d) : "v"(a), "v"(b)); return d;
}
static __device__ __forceinline__ u32 pk_relu(u32 a) {
    u32 d; asm("v_pk_max_f16 %0, %1, 0" : "=v"(d) : "v"(a)); return d;
}

// ---------------------------------------------------------------------------
// Prepack: W1a (256x256), W1b (64x256), W2 (256x128) -> f16 MFMA A-operand
// fragment layout for 32x32x16: frag[mt][ks][lane][j] = W[k][col],
// k = 16*ks + 8*(lane>>5) + j, col = 32*mt + (lane&31).
// ---------------------------------------------------------------------------
__global__ __launch_bounds__(256) void prepack(
    const float* __restrict__ W1, const float* __restrict__ W2,
    f16* __restrict__ pa, f16* __restrict__ pb, f16* __restrict__ pc)
{
    const int idx = blockIdx.x * 256 + threadIdx.x;   // grid covers 114688
    int rel, fid, mt, ks;
    const int lane = (idx >> 3) & 63;
    const int j    = idx & 7;
    const int g8   = ((lane >> 5) << 3) + j;          // 8*(lane>>5)+j
    const int ln   = lane & 31;
    if (idx < 65536) {                 // W1a: [8 mt][16 ks]
        rel = idx; fid = rel >> 9; mt = fid >> 4; ks = fid & 15;
        int k = 16 * ks + g8, col = 32 * mt + ln;
        pa[rel] = (f16)W1[k * 256 + col];
    } else if (idx < 81920) {          // W1b: [8 mt][4 ks]
        rel = idx - 65536; fid = rel >> 9; mt = fid >> 2; ks = fid & 3;
        int k = 16 * ks + g8, col = 32 * mt + ln;
        pb[rel] = (f16)W1[(256 + k) * 256 + col];
    } else {                           // W2: [4 mt][16 ks]
        rel = idx - 81920; fid = rel >> 9; mt = fid >> 4; ks = fid & 15;
        int k = 16 * ks + g8, col = 32 * mt + ln;
        pc[rel] = (f16)W2[k * 128 + col];
    }
}

// ---------------------------------------------------------------------------
// Kernel 1: A[ir][c] = sum_k h[ir][k] * W1a[k][c] + b1[c], stored f16 in a
// gather-friendly permuted layout: uint2 index = ir*64 + g*32 + mt*4 + q.
// ---------------------------------------------------------------------------
__global__ __launch_bounds__(256) void ainit(
    const float* __restrict__ H,       // [16384, 256]
    const f16x8* __restrict__ pW1a,    // [8][16][64] frags
    const float* __restrict__ B1,      // [256]
    f16* __restrict__ Af)              // [16384, 256] permuted
{
    const int tid = threadIdx.x, wid = tid >> 6, lane = tid & 63;
    const int g = lane >> 5, ln = lane & 31;
    const long ir = (long)blockIdx.x * 32 + ln;

    const float4* h4 = (const float4*)(H + ir * 256);
    f16x8 hf[16];
    #pragma unroll
    for (int ks = 0; ks < 16; ++ks)
        hf[ks] = cvt8(h4[4 * ks + 2 * g], h4[4 * ks + 2 * g + 1]);

    const float4* b14 = (const float4*)B1;
    #pragma unroll
    for (int mi = 0; mi < 2; ++mi) {
        const int mt = wid * 2 + mi;
        f32x16 acc;
        #pragma unroll
        for (int q = 0; q < 4; ++q) {
            float4 bv = b14[8 * mt + 2 * q + g];
            acc[4*q+0] = bv.x; acc[4*q+1] = bv.y; acc[4*q+2] = bv.z; acc[4*q+3] = bv.w;
        }
        #pragma unroll
        for (int ks = 0; ks < 16; ++ks)
            acc = MFMA32(pW1a[(mt * 16 + ks) * 64 + lane], hf[ks], acc, 0, 0, 0);
        #pragma unroll
        for (int q = 0; q < 4; ++q) {
            uint2 w;
            w.x = pack2(acc[4*q+0], acc[4*q+1]);
            w.y = pack2(acc[4*q+2], acc[4*q+3]);
            ((uint2*)Af)[ir * 64 + g * 32 + mt * 4 + q] = w;
        }
    }
}

// ---------------------------------------------------------------------------
// Fused: h1 = relu(me@W1b + A[seg]); h2 = relu(h1@W2 + b2); out = h2@W3 + b3
// 512 blocks x 8 waves, NT=4 tiles/wave. W1b+W2 staged to 96KB LDS once;
// barrier-free main loop; Af prefetched a full tile ahead (in-place refill);
// ME refilled in place after fragment build. 2 waves/SIMD.
// ---------------------------------------------------------------------------
__global__ __launch_bounds__(512, 2) void fused_mlp(
    const float* __restrict__ ME,      // [524288, 64]
    const int*   __restrict__ SEG,     // [16384]
    const f16*   __restrict__ Af,      // [16384, 256] permuted
    const f16x8* __restrict__ pW1b,    // [8][4][64] frags
    const f16x8* __restrict__ pW2,     // [4][16][64] frags
    const float* __restrict__ B2,      // [128]
    const float* __restrict__ W3,      // [128]
    const float* __restrict__ B3,      // [1]
    float* __restrict__ OUT)           // [524288]
{
    __shared__ f16x8 sW1b[2048];       // 32 KB
    __shared__ f16x8 sW2[4096];        // 64 KB
    const int tid = threadIdx.x, wid = tid >> 6, lane = tid & 63;
    const int g = lane >> 5, ln = lane & 31;

    #pragma unroll
    for (int i = 0; i < 4; ++i) sW1b[i * 512 + tid] = pW1b[i * 512 + tid];
    #pragma unroll
    for (int i = 0; i < 8; ++i) sW2[i * 512 + tid]  = pW2[i * 512 + tid];
    __syncthreads();

    // XCD-bijective block swizzle (512 % 8 == 0): contiguous 64-block chunks
    const int bswz = (blockIdx.x & 7) * 64 + (blockIdx.x >> 3);
    const long gwave    = (long)bswz * 8 + wid;       // 4096 waves
    const long row_base = gwave * (NT * 32);          // 128 rows per wave

    // prologue: segment-gather rows for all NT tiles
    int arow[NT];
    #pragma unroll
    for (int t = 0; t < NT; ++t) {
        const long gr = row_base + t * 32 + ln;
        arow[t] = ((int)(gr >> 14) << 9) + SEG[(int)(gr & 16383)];
    }

    const uint4* AB = (const uint4*)Af;   // 16B units: row*32 + g*16 + u

    // full-tile Af prefetch buffer (64 VGPR) + ME buffer (32 VGPR)
    uint4 Av[16];
    #pragma unroll
    for (int u = 0; u < 16; ++u) Av[u] = AB[(long)arow[0] * 32 + g * 16 + u];
    float4 Mv[8];
    {
        const float4* mb = (const float4*)(ME + (row_base + ln) * 64);
        #pragma unroll
        for (int s = 0; s < 4; ++s) {
            Mv[2*s]   = mb[4*s + 2*g];
            Mv[2*s+1] = mb[4*s + 2*g + 1];
        }
    }

    const float4* b24 = (const float4*)B2;
    const float4* w34 = (const float4*)W3;
    const float  b3v  = B3[0];

    #pragma unroll
    for (int t = 0; t < NT; ++t) {
        // build ME fragments, then refill Mv in place for tile t+1
        f16x8 mef[4];
        #pragma unroll
        for (int s = 0; s < 4; ++s) mef[s] = cvt8(Mv[2*s], Mv[2*s+1]);
        if (t < NT - 1) {
            const float4* mb = (const float4*)(ME + (row_base + (t+1)*32 + ln) * 64);
            #pragma unroll
            for (int s = 0; s < 4; ++s) {
                Mv[2*s]   = mb[4*s + 2*g];
                Mv[2*s+1] = mb[4*s + 2*g + 1];
            }
        }

        f32x16 acc2[4];
        #pragma unroll
        for (int m2 = 0; m2 < 4; ++m2)
            #pragma unroll
            for (int i = 0; i < 16; ++i) acc2[m2][i] = 0.f;

        #pragma unroll
        for (int mt = 0; mt < 8; ++mt) {
            // consume this mt's gathered A chunk, then refill for tile t+1
            const uint4 a0 = Av[2*mt], a1 = Av[2*mt+1];
            if (t < NT - 1) {
                Av[2*mt]   = AB[(long)arow[t+1] * 32 + g * 16 + 2*mt];
                Av[2*mt+1] = AB[(long)arow[t+1] * 32 + g * 16 + 2*mt + 1];
            }

            // layer-1 partial: me @ W1b (this mt's 32 cols), from LDS
            f32x16 acc;
            #pragma unroll
            for (int i = 0; i < 16; ++i) acc[i] = 0.f;
            #pragma unroll
            for (int s = 0; s < 4; ++s)
                acc = MFMA32(sW1b[(mt * 4 + s) * 64 + lane], mef[s], acc, 0, 0, 0);

            // h1 = relu(A + mw) in packed f16
            u32 hpt[8];
            hpt[0] = pk_relu(pk_add(pack2(acc[0],  acc[1]),  a0.x));
            hpt[1] = pk_relu(pk_add(pack2(acc[2],  acc[3]),  a0.y));
            hpt[2] = pk_relu(pk_add(pack2(acc[4],  acc[5]),  a0.z));
            hpt[3] = pk_relu(pk_add(pack2(acc[6],  acc[7]),  a0.w));
            hpt[4] = pk_relu(pk_add(pack2(acc[8],  acc[9]),  a1.x));
            hpt[5] = pk_relu(pk_add(pack2(acc[10], acc[11]), a1.y));
            hpt[6] = pk_relu(pk_add(pack2(acc[12], acc[13]), a1.z));
            hpt[7] = pk_relu(pk_add(pack2(acc[14], acc[15]), a1.w));

            // layer-2 feed: ks2 = 2*mt + tt, W2 from LDS
            #pragma unroll
            for (int tt = 0; tt < 2; ++tt) {
                u32 w0 = hpt[4*tt+0], w1 = hpt[4*tt+1];
                u32 w2 = hpt[4*tt+2], w3 = hpt[4*tt+3];
                asm("v_permlane32_swap_b32 %0, %1" : "+v"(w0), "+v"(w2));
                asm("v_permlane32_swap_b32 %0, %1" : "+v"(w1), "+v"(w3));
                int wv[4] = {(int)w0, (int)w1, (int)w2, (int)w3};
                f16x8 bf;
                __builtin_memcpy(&bf, wv, 16);
                const int ks2 = 2 * mt + tt;
                __builtin_amdgcn_s_setprio(1);
                #pragma unroll
                for (int m2 = 0; m2 < 4; ++m2)
                    acc2[m2] = MFMA32(sW2[(m2 * 16 + ks2) * 64 + lane], bf, acc2[m2], 0, 0, 0);
                __builtin_amdgcn_s_setprio(0);
            }
        }

        // phase 3: out = relu(h2 + b2) . W3 + b3
        float sum = 0.f;
        #pragma unroll
        for (int m2 = 0; m2 < 4; ++m2)
            #pragma unroll
            for (int q = 0; q < 4; ++q) {
                float4 bb = b24[8*m2 + 2*q + g];
                float4 ww = w34[8*m2 + 2*q + g];
                sum += fmaxf(acc2[m2][4*q+0] + bb.x, 0.f) * ww.x
                     + fmaxf(acc2[m2][4*q+1] + bb.y, 0.f) * ww.y
                     + fmaxf(acc2[m2][4*q+2] + bb.z, 0.f) * ww.z
                     + fmaxf(acc2[m2][4*q+3] + bb.w, 0.f) * ww.w;
            }
        sum += __shfl_xor(sum, 32, 64);     // combine the two g column-halves
        if (lane < 32) OUT[row_base + t * 32 + ln] = sum + b3v;
    }
}

// ---------------------------------------------------------------------------
extern "C" void kernel_launch(void* const* d_in, const int* in_sizes, int n_in,
                              void* d_out, int out_size, void* d_ws, size_t ws_size,
                              hipStream_t stream) {
    const float* h_inst = (const float*)d_in[0];
    const float* me     = (const float*)d_in[1];
    const int*   seg    = (const int*)d_in[2];
    const float* W1     = (const float*)d_in[3];
    const float* b1     = (const float*)d_in[4];
    const float* W2     = (const float*)d_in[5];
    const float* b2     = (const float*)d_in[6];
    const float* W3     = (const float*)d_in[7];
    const float* b3     = (const float*)d_in[8];
    float* out = (float*)d_out;

    char* ws = (char*)d_ws;
    f16* Af   = (f16*)ws;                                   // 8,388,608 B
    f16* pW1a = (f16*)(ws + 8388608);                       //   131,072 B
    f16* pW1b = (f16*)(ws + 8388608 + 131072);              //    32,768 B
    f16* pW2  = (f16*)(ws + 8388608 + 131072 + 32768);      //    65,536 B

    prepack<<<448, 256, 0, stream>>>(W1, W2, pW1a, pW1b, pW2);
    ainit<<<512, 256, 0, stream>>>(h_inst, (const f16x8*)pW1a, b1, Af);
    fused_mlp<<<512, 512, 0, stream>>>(me, seg, Af, (const f16x8*)pW1b,
                                       (const f16x8*)pW2, b2, W3, b3, out);
}